// Round 8
// baseline (191.121 us; speedup 1.0000x reference)
//
#include <hip/hip_runtime.h>
#include <math.h>

#define N_NODES 50000
#define N_EDGES 800000
#define NFEAT 256
#define NHID 64
#define NCLASS 2

// buckets: node>>6 -> 782 buckets of 64 nodes (R7 post-mortem: 196-block
// dfin/sfin = <1 block/CU latency-bound; 782 -> ~3 blocks/CU)
#define DB 64
#define NDB 782
#define BCAP 1536        // mean 1024, sigma 32 -> +16 sigma headroom
#define EPB 2048         // edges per scatter block (8/thread) -> 391 blocks
#define NB_EDGE ((N_EDGES + EPB - 1) / EPB)

// ---------------- workspace layout (4-byte units) ----------------
#define OFF_CURD 0        // int[800]   dst-bucket cursors (memset 0)
#define OFF_CURS 800      // int[800]   src-bucket cursors (memset 0)
#define OFF_RB   1600     // int[50000] row_beg (absolute into csr)
#define OFF_DEG  51600    // int[50000] in-degree
#define OFF_NDST 101600   // f32[50000]
#define OFF_NSRC 151600   // f32[50000]
#define OFF_W1T  201600   // bf16[64*256] transposed W1 = 8192 words
#define OFF_DPK  209792   // int[782*1536=1201152] packed (src<<6|dst&63)
#define OFF_SV6  1410944  // uchar[1201152] (src&63) by src>>6 = 300288 words
#define OFF_CSR  1711232  // int[1201152] csr src ids
#define OFF_HB   2912384  // bf16[50000*64] = 1600000 words
#define OFF_H2   4512384  // f32[100000]

typedef __attribute__((ext_vector_type(8))) short bf16x8;
typedef __attribute__((ext_vector_type(8))) short short8;
typedef __attribute__((ext_vector_type(4))) float f32x4;

// fast fp32->bf16, round-to-nearest-away (0.5 ulp, 2 VALU ops)
static __device__ __forceinline__ unsigned short f2bf(float f) {
    union { float f; unsigned int u; } v; v.f = f;
    return (unsigned short)((v.u + 0x8000u) >> 16);
}
// pack two fp32 -> two bf16 in one dword: 2 adds + v_perm
static __device__ __forceinline__ unsigned int pk2bf(float f0, float f1) {
    union { float f; unsigned int u; } a, b; a.f = f0; b.f = f1;
    return __builtin_amdgcn_perm(b.u + 0x8000u, a.u + 0x8000u, 0x07060302u);
}
static __device__ __forceinline__ float bflo(unsigned int u) {
    union { unsigned int x; float f; } v; v.x = u << 16; return v.f;
}
static __device__ __forceinline__ float bfhi(unsigned int u) {
    union { unsigned int x; float f; } v; v.x = u & 0xffff0000u; return v.f;
}

// K0: W1[256][64] fp32 -> W1T[64][256] bf16 (one-time, tiny)
__global__ __launch_bounds__(256) void w1cvt_kernel(const float* __restrict__ W1,
                                                    unsigned short* __restrict__ w1t) {
    int idx = blockIdx.x * 256 + threadIdx.x;
    if (idx < NFEAT * NHID) {
        int k = idx >> 6, n = idx & 63;
        w1t[n * NFEAT + k] = f2bf(W1[idx]);
    }
}

// K1: partition edges into fixed-capacity dst-buckets (packed src<<6|dstlow)
// and src-buckets (src&63 bytes). LDS hist -> one global atomic per bucket.
__global__ __launch_bounds__(256) void bscatter_kernel(const int* __restrict__ src,
                                                       const int* __restrict__ dst,
                                                       int* __restrict__ cur_d,
                                                       int* __restrict__ cur_s,
                                                       int* __restrict__ dpk,
                                                       unsigned char* __restrict__ sv6) {
    __shared__ int hd[NDB], bd[NDB], cd[NDB], hs[NDB], bs[NDB], cs[NDB];
    int t = threadIdx.x;
    for (int i = t; i < NDB; i += 256) { hd[i] = 0; cd[i] = 0; hs[i] = 0; cs[i] = 0; }
    __syncthreads();
    int base = blockIdx.x * EPB;
    int ls[8], ld[8];
#pragma unroll
    for (int i = 0; i < 8; ++i) {
        int e = base + t + i * 256;
        ls[i] = (e < N_EDGES) ? src[e] : -1;
        ld[i] = (e < N_EDGES) ? dst[e] : -1;
        if (ld[i] >= 0) {
            atomicAdd(&hd[ld[i] >> 6], 1);
            atomicAdd(&hs[ls[i] >> 6], 1);
        }
    }
    __syncthreads();
    for (int i = t; i < NDB; i += 256) {
        if (hd[i]) bd[i] = atomicAdd(&cur_d[i], hd[i]);
        if (hs[i]) bs[i] = atomicAdd(&cur_s[i], hs[i]);
    }
    __syncthreads();
#pragma unroll
    for (int i = 0; i < 8; ++i) {
        if (ld[i] >= 0) {
            int bin = ld[i] >> 6;
            int pos = bd[bin] + atomicAdd(&cd[bin], 1);
            dpk[bin * BCAP + pos] = (ls[i] << 6) | (ld[i] & 63);
            int sbin = ls[i] >> 6;
            int spos = bs[sbin] + atomicAdd(&cs[sbin], 1);
            sv6[sbin * BCAP + spos] = (unsigned char)(ls[i] & 63);
        }
    }
}

// K2: per 64-node dst-bucket: stage edges in LDS, 64-bin hist (4 sub-hists),
// scan, rank -> csr + row_beg/deg/norm_dst. No global atomics.
__global__ __launch_bounds__(256) void dfin_kernel(const int* __restrict__ cur_d,
                                                   const int* __restrict__ dpk,
                                                   int* __restrict__ row_beg,
                                                   int* __restrict__ degv,
                                                   float* __restrict__ norm_dst,
                                                   int* __restrict__ csr) {
    __shared__ int ebuf[BCAP];           // 6 KB
    __shared__ int hist4[4 * 64], hist[64], seg[64], cur[64];
    int b = blockIdx.x, t = threadIdx.x;
    int cnt = cur_d[b];
    int base = b * BCAP;
    if (t < 64) { hist[t] = 0; cur[t] = 0; }
    hist4[t] = 0;
    for (int j = t; j < cnt; j += 256) ebuf[j] = dpk[base + j];
    __syncthreads();
    int sub = (t & 3) * 64;
    for (int j = t; j < cnt; j += 256) atomicAdd(&hist4[sub + (ebuf[j] & 63)], 1);
    __syncthreads();
    if (t < 64) {
        int v = hist4[t] + hist4[64 + t] + hist4[128 + t] + hist4[192 + t];
        hist[t] = v;
        seg[t] = v;
    }
    __syncthreads();
#pragma unroll
    for (int off = 1; off < 64; off <<= 1) {
        int xv = 0;
        if (t < 64 && t >= off) xv = seg[t - off];
        __syncthreads();
        if (t < 64) seg[t] += xv;
        __syncthreads();
    }
    if (t < 64) {
        int v = hist[t];
        int excl = seg[t] - v;
        int gid = b * 64 + t;
        if (gid < N_NODES) {
            row_beg[gid] = base + excl;
            degv[gid] = v;
            norm_dst[gid] = rsqrtf(fmaxf((float)v, 1.0f));
        }
        seg[t] = excl;
    }
    __syncthreads();
    for (int j = t; j < cnt; j += 256) {
        int p = ebuf[j];
        int dlow = p & 63;
        int pos = base + seg[dlow] + atomicAdd(&cur[dlow], 1);
        csr[pos] = ((unsigned)p) >> 6;
    }
}

// K3: per 64-node src-bucket: out-degree hist -> norm_src
__global__ __launch_bounds__(256) void sfin_kernel(const int* __restrict__ cur_s,
                                                   const unsigned char* __restrict__ sv6,
                                                   float* __restrict__ norm_src) {
    __shared__ int hist4[4 * 64];
    int b = blockIdx.x, t = threadIdx.x;
    hist4[t] = 0;
    __syncthreads();
    int cnt = cur_s[b];
    int base = b * BCAP;
    int sub = (t & 3) * 64;
    for (int j = t; j < cnt; j += 256) atomicAdd(&hist4[sub + sv6[base + j]], 1);
    __syncthreads();
    if (t < 64) {
        int gid = b * 64 + t;
        if (gid < N_NODES) {
            int v = hist4[t] + hist4[64 + t] + hist4[128 + t] + hist4[192 + t];
            norm_src[gid] = rsqrtf(fmaxf((float)v, 1.0f));
        }
    }
}

// K4: hb[50000x64] = bf16( norm_src[:,None] * (x @ W1) ), MFMA.
// A staged as bf16 via packed cvt (no norm); B copied from pre-converted W1T;
// norm applied in fp32 epilogue (commutes with the row-scaled GEMM).
#define LDA 264
__global__ __launch_bounds__(256) void gemm1_kernel(const float* __restrict__ x,
                                                    const unsigned short* __restrict__ w1t,
                                                    const float* __restrict__ norm_src,
                                                    unsigned short* __restrict__ hb) {
    __shared__ unsigned short As[64][LDA];
    __shared__ unsigned short Bs[64][LDA];
    const int t = threadIdx.x;
    const int row0 = blockIdx.x * 64;
    // stage A: 64x256 fp32 -> bf16 (packed cvt, no norm)
#pragma unroll
    for (int i = 0; i < 16; ++i) {
        int f = i * 256 + t;          // float4 index
        int r = f >> 6;
        int c4 = (f & 63) * 4;
        int grow = row0 + r;
        float4 av = make_float4(0.f, 0.f, 0.f, 0.f);
        if (grow < N_NODES) av = *(const float4*)(&x[(size_t)grow * NFEAT + c4]);
        uint2 o;
        o.x = pk2bf(av.x, av.y);
        o.y = pk2bf(av.z, av.w);
        *(uint2*)(&As[r][c4]) = o;
    }
    // stage B: straight bf16 copy of W1T rows (64x256 shorts, short8 chunks)
#pragma unroll
    for (int i = 0; i < 8; ++i) {
        int c = i * 256 + t;          // short8 chunk id, 2048 total
        int n = c >> 5;
        int k8 = (c & 31) * 8;
        *(short8*)(&Bs[n][k8]) = *(const short8*)(&w1t[n * NFEAT + k8]);
    }
    __syncthreads();
    const int w = t >> 6;
    const int l = t & 63;
    const int m = l & 15;
    const int kq = (l >> 4) * 8;
    f32x4 acc[4] = {{0.f, 0.f, 0.f, 0.f}, {0.f, 0.f, 0.f, 0.f},
                    {0.f, 0.f, 0.f, 0.f}, {0.f, 0.f, 0.f, 0.f}};
#pragma unroll
    for (int c8 = 0; c8 < 8; ++c8) {
        int k0 = c8 * 32 + kq;
        bf16x8 a = *(const bf16x8*)(&As[w * 16 + m][k0]);
#pragma unroll
        for (int ct = 0; ct < 4; ++ct) {
            bf16x8 b = *(const bf16x8*)(&Bs[ct * 16 + m][k0]);
            acc[ct] = __builtin_amdgcn_mfma_f32_16x16x32_bf16(a, b, acc[ct], 0, 0, 0);
        }
    }
    const int q = l >> 4;
#pragma unroll
    for (int reg = 0; reg < 4; ++reg) {
        int r = row0 + w * 16 + q * 4 + reg;
        if (r < N_NODES) {
            float ns = norm_src[r];
#pragma unroll
            for (int ct = 0; ct < 4; ++ct)
                hb[(size_t)r * NHID + ct * 16 + m] = f2bf(acc[ct][reg] * ns);
        }
    }
}

// K5: fused layer1, node-major, register accumulation, 16 edges in flight
// per wave (2 unrolled dwordx4 x 8 edge-slots). lane = e8*8 + fg.
__global__ __launch_bounds__(256) void fused1_kernel(const int* __restrict__ row_beg,
                                                     const int* __restrict__ degv,
                                                     const int* __restrict__ csr,
                                                     const unsigned short* __restrict__ hb,
                                                     const float* __restrict__ norm_dst,
                                                     const float* __restrict__ norm_src,
                                                     const float* __restrict__ b1,
                                                     const float* __restrict__ W2,
                                                     float* __restrict__ h2) {
    int gtid = blockIdx.x * blockDim.x + threadIdx.x;
    int node = gtid >> 6;
    int lane = gtid & 63;
    if (node >= N_NODES) return;
    int e8 = lane >> 3, fg = lane & 7;
    int beg = row_beg[node];
    int end = beg + degv[node];
    float a0 = 0.f, a1 = 0.f, a2 = 0.f, a3 = 0.f, a4 = 0.f, a5 = 0.f, a6 = 0.f, a7 = 0.f;
    for (int j = beg; j < end; j += 16) {
        int j0 = j + e8, j1 = j0 + 8;
        uint4 u0 = make_uint4(0u, 0u, 0u, 0u), u1 = make_uint4(0u, 0u, 0u, 0u);
        if (j0 < end) u0 = *(const uint4*)(&hb[(size_t)csr[j0] * NHID + fg * 8]);
        if (j1 < end) u1 = *(const uint4*)(&hb[(size_t)csr[j1] * NHID + fg * 8]);
        a0 += bflo(u0.x) + bflo(u1.x);
        a1 += bfhi(u0.x) + bfhi(u1.x);
        a2 += bflo(u0.y) + bflo(u1.y);
        a3 += bfhi(u0.y) + bfhi(u1.y);
        a4 += bflo(u0.z) + bflo(u1.z);
        a5 += bfhi(u0.z) + bfhi(u1.z);
        a6 += bflo(u0.w) + bflo(u1.w);
        a7 += bfhi(u0.w) + bfhi(u1.w);
    }
#pragma unroll
    for (int off = 8; off <= 32; off <<= 1) {
        a0 += __shfl_xor(a0, off, 64);
        a1 += __shfl_xor(a1, off, 64);
        a2 += __shfl_xor(a2, off, 64);
        a3 += __shfl_xor(a3, off, 64);
        a4 += __shfl_xor(a4, off, 64);
        a5 += __shfl_xor(a5, off, 64);
        a6 += __shfl_xor(a6, off, 64);
        a7 += __shfl_xor(a7, off, 64);
    }
    float nd = norm_dst[node], ns = norm_src[node];
    float4 bv0 = *(const float4*)(&b1[fg * 8]);
    float4 bv1 = *(const float4*)(&b1[fg * 8 + 4]);
    float4 w0 = *(const float4*)(&W2[fg * 16 + 0]);
    float4 w1 = *(const float4*)(&W2[fg * 16 + 4]);
    float4 w2v = *(const float4*)(&W2[fg * 16 + 8]);
    float4 w3 = *(const float4*)(&W2[fg * 16 + 12]);
    float h0 = fmaxf(fmaf(a0, nd, bv0.x), 0.f) * ns;
    float h1 = fmaxf(fmaf(a1, nd, bv0.y), 0.f) * ns;
    float h2f = fmaxf(fmaf(a2, nd, bv0.z), 0.f) * ns;
    float h3 = fmaxf(fmaf(a3, nd, bv0.w), 0.f) * ns;
    float h4 = fmaxf(fmaf(a4, nd, bv1.x), 0.f) * ns;
    float h5 = fmaxf(fmaf(a5, nd, bv1.y), 0.f) * ns;
    float h6 = fmaxf(fmaf(a6, nd, bv1.z), 0.f) * ns;
    float h7 = fmaxf(fmaf(a7, nd, bv1.w), 0.f) * ns;
    float p0 = h0 * w0.x + h1 * w0.z + h2f * w1.x + h3 * w1.z +
               h4 * w2v.x + h5 * w2v.z + h6 * w3.x + h7 * w3.z;
    float p1 = h0 * w0.y + h1 * w0.w + h2f * w1.y + h3 * w1.w +
               h4 * w2v.y + h5 * w2v.w + h6 * w3.y + h7 * w3.w;
#pragma unroll
    for (int off = 1; off <= 4; off <<= 1) {
        p0 += __shfl_xor(p0, off, 64);
        p1 += __shfl_xor(p1, off, 64);
    }
    if (lane == 0) *(float2*)(&h2[node * 2]) = make_float2(p0, p1);
}

// K6: fused layer2 per dst node (one thread): agg h2 -> logits -> log_softmax
__global__ void fused2_kernel(const int* __restrict__ row_beg, const int* __restrict__ degv,
                              const int* __restrict__ csr, const float* __restrict__ h2,
                              const float* __restrict__ norm_dst, const float* __restrict__ b2,
                              float* __restrict__ out) {
    int n = blockIdx.x * blockDim.x + threadIdx.x;
    if (n >= N_NODES) return;
    int beg = row_beg[n], end = beg + degv[n];
    float s0 = 0.f, s1 = 0.f;
    for (int j = beg; j < end; ++j) {
        float2 v = *(const float2*)(&h2[csr[j] * 2]);
        s0 += v.x;
        s1 += v.y;
    }
    float nd = norm_dst[n];
    float l0 = fmaf(s0, nd, b2[0]);
    float l1 = fmaf(s1, nd, b2[1]);
    float m = fmaxf(l0, l1);
    float lse = m + logf(expf(l0 - m) + expf(l1 - m));
    *(float2*)(&out[n * 2]) = make_float2(l0 - lse, l1 - lse);
}

extern "C" void kernel_launch(void* const* d_in, const int* in_sizes, int n_in,
                              void* d_out, int out_size, void* d_ws, size_t ws_size,
                              hipStream_t stream) {
    const float* x  = (const float*)d_in[0];
    const int* src  = (const int*)d_in[1];
    const int* dst  = (const int*)d_in[2];
    const float* W1 = (const float*)d_in[3];
    const float* b1 = (const float*)d_in[4];
    const float* W2 = (const float*)d_in[5];
    const float* b2 = (const float*)d_in[6];
    float* out = (float*)d_out;
    float* ws  = (float*)d_ws;
    int*   wsi = (int*)d_ws;

    int*   cur_d    = wsi + OFF_CURD;
    int*   cur_s    = wsi + OFF_CURS;
    int*   row_beg  = wsi + OFF_RB;
    int*   degv     = wsi + OFF_DEG;
    float* norm_dst = ws + OFF_NDST;
    float* norm_src = ws + OFF_NSRC;
    unsigned short* w1t = (unsigned short*)(wsi + OFF_W1T);
    int*   dpk      = wsi + OFF_DPK;
    unsigned char* sv6 = (unsigned char*)(wsi + OFF_SV6);
    int*   csr      = wsi + OFF_CSR;
    unsigned short* hb = (unsigned short*)(wsi + OFF_HB);
    float* h2       = ws + OFF_H2;

    hipMemsetAsync(cur_d, 0, 1600 * sizeof(int), stream);
    w1cvt_kernel<<<(NFEAT * NHID + 255) / 256, 256, 0, stream>>>(W1, w1t);
    bscatter_kernel<<<NB_EDGE, 256, 0, stream>>>(src, dst, cur_d, cur_s, dpk, sv6);
    sfin_kernel<<<NDB, 256, 0, stream>>>(cur_s, sv6, norm_src);
    dfin_kernel<<<NDB, 256, 0, stream>>>(cur_d, dpk, row_beg, degv, norm_dst, csr);
    gemm1_kernel<<<(N_NODES + 63) / 64, 256, 0, stream>>>(x, w1t, norm_src, hb);
    {
        long long threads = (long long)N_NODES * 64;
        fused1_kernel<<<(int)((threads + 255) / 256), 256, 0, stream>>>(
            row_beg, degv, csr, hb, norm_dst, norm_src, b1, W2, h2);
    }
    fused2_kernel<<<(N_NODES + 255) / 256, 256, 0, stream>>>(row_beg, degv, csr, h2, norm_dst, b2, out);
}

// Round 9
// 184.325 us; speedup vs baseline: 1.0369x; 1.0369x over previous
//
#include <hip/hip_runtime.h>
#include <math.h>

#define N_NODES 50000
#define N_EDGES 800000
#define NFEAT 256
#define NHID 64
#define NCLASS 2

// buckets: node>>6 -> 782 buckets of 64 nodes
#define DB 64
#define NDB 782
#define BCAP 1536        // mean 1024, sigma 32 -> +16 sigma headroom
#define EPB 2048         // edges per scatter block (8/thread) -> 391 blocks
#define NB_EDGE ((N_EDGES + EPB - 1) / EPB)

// ---------------- workspace layout (4-byte units) ----------------
#define OFF_CURD 0        // int[800]   dst-bucket cursors (zeroed by init)
#define OFF_CURS 800      // int[800]   src-bucket cursors (zeroed by init)
#define OFF_RB   1600     // int[50000] row_beg (absolute into csr)
#define OFF_DEG  51600    // int[50000] in-degree
#define OFF_NDST 101600   // f32[50000]
#define OFF_NSRC 151600   // f32[50000]
#define OFF_W1T  201600   // bf16[64*256] transposed W1 = 8192 words
#define OFF_DPK  209792   // int[782*1536=1201152] packed (src<<6|dst&63)
#define OFF_SV6  1410944  // uchar[1201152] (src&63) by src>>6 = 300288 words
#define OFF_CSR  1711232  // int[1201152] csr src ids
#define OFF_HB   2912384  // bf16[50000*64] = 1600000 words (UN-normed x@W1)
#define OFF_H2   4512384  // f32[100000]

typedef __attribute__((ext_vector_type(8))) short bf16x8;
typedef __attribute__((ext_vector_type(8))) short short8;
typedef __attribute__((ext_vector_type(4))) float f32x4;

// fast fp32->bf16, round-to-nearest-away (0.5 ulp, 2 VALU ops)
static __device__ __forceinline__ unsigned short f2bf(float f) {
    union { float f; unsigned int u; } v; v.f = f;
    return (unsigned short)((v.u + 0x8000u) >> 16);
}
// pack two fp32 -> two bf16 in one dword: 2 adds + v_perm
static __device__ __forceinline__ unsigned int pk2bf(float f0, float f1) {
    union { float f; unsigned int u; } a, b; a.f = f0; b.f = f1;
    return __builtin_amdgcn_perm(b.u + 0x8000u, a.u + 0x8000u, 0x07060302u);
}
static __device__ __forceinline__ float bflo(unsigned int u) {
    union { unsigned int x; float f; } v; v.x = u << 16; return v.f;
}
static __device__ __forceinline__ float bfhi(unsigned int u) {
    union { unsigned int x; float f; } v; v.x = u & 0xffff0000u; return v.f;
}

// K0: zero bucket cursors + W1 -> W1T bf16 (one launch, tiny)
#define INIT_N (1600 + NFEAT * NHID)
__global__ __launch_bounds__(256) void init_kernel(const float* __restrict__ W1,
                                                   int* __restrict__ cursors,
                                                   unsigned short* __restrict__ w1t) {
    int g = blockIdx.x * 256 + threadIdx.x;
    if (g < 1600) {
        cursors[g] = 0;
    } else if (g < INIT_N) {
        int idx = g - 1600;
        int k = idx >> 6, n = idx & 63;
        w1t[n * NFEAT + k] = f2bf(W1[idx]);
    }
}

// K1: partition edges into fixed-capacity dst-buckets (packed src<<6|dstlow)
// and src-buckets (src&63 bytes). LDS hist -> one global atomic per bucket.
__global__ __launch_bounds__(256) void bscatter_kernel(const int* __restrict__ src,
                                                       const int* __restrict__ dst,
                                                       int* __restrict__ cur_d,
                                                       int* __restrict__ cur_s,
                                                       int* __restrict__ dpk,
                                                       unsigned char* __restrict__ sv6) {
    __shared__ int hd[NDB], bd[NDB], cd[NDB], hs[NDB], bs[NDB], cs[NDB];
    int t = threadIdx.x;
    for (int i = t; i < NDB; i += 256) { hd[i] = 0; cd[i] = 0; hs[i] = 0; cs[i] = 0; }
    __syncthreads();
    int base = blockIdx.x * EPB;
    int ls[8], ld[8];
#pragma unroll
    for (int i = 0; i < 8; ++i) {
        int e = base + t + i * 256;
        ls[i] = (e < N_EDGES) ? src[e] : -1;
        ld[i] = (e < N_EDGES) ? dst[e] : -1;
        if (ld[i] >= 0) {
            atomicAdd(&hd[ld[i] >> 6], 1);
            atomicAdd(&hs[ls[i] >> 6], 1);
        }
    }
    __syncthreads();
    for (int i = t; i < NDB; i += 256) {
        if (hd[i]) bd[i] = atomicAdd(&cur_d[i], hd[i]);
        if (hs[i]) bs[i] = atomicAdd(&cur_s[i], hs[i]);
    }
    __syncthreads();
#pragma unroll
    for (int i = 0; i < 8; ++i) {
        if (ld[i] >= 0) {
            int bin = ld[i] >> 6;
            int pos = bd[bin] + atomicAdd(&cd[bin], 1);
            dpk[bin * BCAP + pos] = (ls[i] << 6) | (ld[i] & 63);
            int sbin = ls[i] >> 6;
            int spos = bs[sbin] + atomicAdd(&cs[sbin], 1);
            sv6[sbin * BCAP + spos] = (unsigned char)(ls[i] & 63);
        }
    }
}

// K2: three independent roles in one launch (all depend only on K1/K0):
//  role 0: sfin  (782 blocks) — out-degree hist -> norm_src
//  role 1: dfin  (782 blocks) — CSR build + norm_dst/deg/row_beg
//  role 2: gemm  (782 blocks) — hb = bf16(x @ W1T), MFMA, un-normed
union MidShared {
    struct { unsigned short As[64][136]; unsigned short Bs[64][264]; } g;  // 51.2 KB
    struct { int ebuf[BCAP]; int hist4[256]; int hist[64]; int seg[64]; int cur[64]; } d;
    struct { int hist4[256]; } s;
};
__global__ __launch_bounds__(256) void mid_kernel(const int* __restrict__ cur_d,
                                                  const int* __restrict__ cur_s,
                                                  const int* __restrict__ dpk,
                                                  const unsigned char* __restrict__ sv6,
                                                  const float* __restrict__ x,
                                                  const unsigned short* __restrict__ w1t,
                                                  int* __restrict__ row_beg,
                                                  int* __restrict__ degv,
                                                  float* __restrict__ norm_dst,
                                                  float* __restrict__ norm_src,
                                                  int* __restrict__ csr,
                                                  unsigned short* __restrict__ hb) {
    __shared__ MidShared su;
    int t = threadIdx.x;
    int role = blockIdx.x % 3;
    int b = blockIdx.x / 3;

    if (role == 0) {
        // ---- sfin: per 64-node src-bucket out-degree hist -> norm_src ----
        su.s.hist4[t] = 0;
        __syncthreads();
        int cnt = cur_s[b];
        int base = b * BCAP;
        int sub = (t & 3) * 64;
        for (int j = t; j < cnt; j += 256) atomicAdd(&su.s.hist4[sub + sv6[base + j]], 1);
        __syncthreads();
        if (t < 64) {
            int gid = b * 64 + t;
            if (gid < N_NODES) {
                int v = su.s.hist4[t] + su.s.hist4[64 + t] + su.s.hist4[128 + t] + su.s.hist4[192 + t];
                norm_src[gid] = rsqrtf(fmaxf((float)v, 1.0f));
            }
        }
    } else if (role == 1) {
        // ---- dfin: stage bucket, 64-bin hist, scan, rank -> csr ----
        int cnt = cur_d[b];
        int base = b * BCAP;
        if (t < 64) { su.d.hist[t] = 0; su.d.cur[t] = 0; }
        su.d.hist4[t] = 0;
        for (int j = t; j < cnt; j += 256) su.d.ebuf[j] = dpk[base + j];
        __syncthreads();
        int sub = (t & 3) * 64;
        for (int j = t; j < cnt; j += 256) atomicAdd(&su.d.hist4[sub + (su.d.ebuf[j] & 63)], 1);
        __syncthreads();
        if (t < 64) {
            int v = su.d.hist4[t] + su.d.hist4[64 + t] + su.d.hist4[128 + t] + su.d.hist4[192 + t];
            su.d.hist[t] = v;
            su.d.seg[t] = v;
        }
        __syncthreads();
#pragma unroll
        for (int off = 1; off < 64; off <<= 1) {
            int xv = 0;
            if (t < 64 && t >= off) xv = su.d.seg[t - off];
            __syncthreads();
            if (t < 64) su.d.seg[t] += xv;
            __syncthreads();
        }
        if (t < 64) {
            int v = su.d.hist[t];
            int excl = su.d.seg[t] - v;
            int gid = b * 64 + t;
            if (gid < N_NODES) {
                row_beg[gid] = base + excl;
                degv[gid] = v;
                norm_dst[gid] = rsqrtf(fmaxf((float)v, 1.0f));
            }
            su.d.seg[t] = excl;
        }
        __syncthreads();
        for (int j = t; j < cnt; j += 256) {
            int p = su.d.ebuf[j];
            int dlow = p & 63;
            int pos = base + su.d.seg[dlow] + atomicAdd(&su.d.cur[dlow], 1);
            csr[pos] = ((unsigned)p) >> 6;
        }
    } else {
        // ---- gemm: 64-row tile, B full-K resident, A staged in 2 K-halves ----
        const int row0 = b * 64;
#pragma unroll
        for (int i = 0; i < 8; ++i) {
            int c = i * 256 + t;          // short8 chunk, 2048 total
            int n = c >> 5;
            int k8 = (c & 31) * 8;
            *(short8*)(&su.g.Bs[n][k8]) = *(const short8*)(&w1t[n * NFEAT + k8]);
        }
        const int w = t >> 6;
        const int l = t & 63;
        const int m = l & 15;
        const int kq = (l >> 4) * 8;
        const int q = l >> 4;
        f32x4 acc[4] = {{0.f, 0.f, 0.f, 0.f}, {0.f, 0.f, 0.f, 0.f},
                        {0.f, 0.f, 0.f, 0.f}, {0.f, 0.f, 0.f, 0.f}};
#pragma unroll
        for (int half = 0; half < 2; ++half) {
            __syncthreads();  // covers B-stage (half 0) and As reuse (half 1)
#pragma unroll
            for (int i = 0; i < 8; ++i) {
                int f = i * 256 + t;      // float4 id within half, 2048 total
                int r = f >> 5;
                int c4 = (f & 31) * 4;
                int grow = row0 + r;
                float4 av = make_float4(0.f, 0.f, 0.f, 0.f);
                if (grow < N_NODES)
                    av = *(const float4*)(&x[(size_t)grow * NFEAT + half * 128 + c4]);
                uint2 o;
                o.x = pk2bf(av.x, av.y);
                o.y = pk2bf(av.z, av.w);
                *(uint2*)(&su.g.As[r][c4]) = o;
            }
            __syncthreads();
#pragma unroll
            for (int c8 = 0; c8 < 4; ++c8) {
                int k0 = c8 * 32 + kq;
                bf16x8 a = *(const bf16x8*)(&su.g.As[w * 16 + m][k0]);
#pragma unroll
                for (int ct = 0; ct < 4; ++ct) {
                    bf16x8 bb = *(const bf16x8*)(&su.g.Bs[ct * 16 + m][half * 128 + k0]);
                    acc[ct] = __builtin_amdgcn_mfma_f32_16x16x32_bf16(a, bb, acc[ct], 0, 0, 0);
                }
            }
        }
#pragma unroll
        for (int reg = 0; reg < 4; ++reg) {
            int r = row0 + w * 16 + q * 4 + reg;
            if (r < N_NODES) {
#pragma unroll
                for (int ct = 0; ct < 4; ++ct)
                    hb[(size_t)r * NHID + ct * 16 + m] = f2bf(acc[ct][reg]);
            }
        }
    }
}

// K3: fused layer1, node-major, register accumulation, 16 edges in flight.
// hb is UN-normed -> apply norm_src[s] per edge via fmaf.
__global__ __launch_bounds__(256) void fused1_kernel(const int* __restrict__ row_beg,
                                                     const int* __restrict__ degv,
                                                     const int* __restrict__ csr,
                                                     const unsigned short* __restrict__ hb,
                                                     const float* __restrict__ norm_dst,
                                                     const float* __restrict__ norm_src,
                                                     const float* __restrict__ b1,
                                                     const float* __restrict__ W2,
                                                     float* __restrict__ h2) {
    int gtid = blockIdx.x * blockDim.x + threadIdx.x;
    int node = gtid >> 6;
    int lane = gtid & 63;
    if (node >= N_NODES) return;
    int e8 = lane >> 3, fg = lane & 7;
    int beg = row_beg[node];
    int end = beg + degv[node];
    float a0 = 0.f, a1 = 0.f, a2 = 0.f, a3 = 0.f, a4 = 0.f, a5 = 0.f, a6 = 0.f, a7 = 0.f;
    for (int j = beg; j < end; j += 16) {
        int j0 = j + e8, j1 = j0 + 8;
        uint4 u0 = make_uint4(0u, 0u, 0u, 0u), u1 = make_uint4(0u, 0u, 0u, 0u);
        float ns0 = 0.f, ns1 = 0.f;
        if (j0 < end) {
            int s = csr[j0];
            ns0 = norm_src[s];
            u0 = *(const uint4*)(&hb[(size_t)s * NHID + fg * 8]);
        }
        if (j1 < end) {
            int s = csr[j1];
            ns1 = norm_src[s];
            u1 = *(const uint4*)(&hb[(size_t)s * NHID + fg * 8]);
        }
        a0 = fmaf(ns0, bflo(u0.x), fmaf(ns1, bflo(u1.x), a0));
        a1 = fmaf(ns0, bfhi(u0.x), fmaf(ns1, bfhi(u1.x), a1));
        a2 = fmaf(ns0, bflo(u0.y), fmaf(ns1, bflo(u1.y), a2));
        a3 = fmaf(ns0, bfhi(u0.y), fmaf(ns1, bfhi(u1.y), a3));
        a4 = fmaf(ns0, bflo(u0.z), fmaf(ns1, bflo(u1.z), a4));
        a5 = fmaf(ns0, bfhi(u0.z), fmaf(ns1, bfhi(u1.z), a5));
        a6 = fmaf(ns0, bflo(u0.w), fmaf(ns1, bflo(u1.w), a6));
        a7 = fmaf(ns0, bfhi(u0.w), fmaf(ns1, bfhi(u1.w), a7));
    }
#pragma unroll
    for (int off = 8; off <= 32; off <<= 1) {
        a0 += __shfl_xor(a0, off, 64);
        a1 += __shfl_xor(a1, off, 64);
        a2 += __shfl_xor(a2, off, 64);
        a3 += __shfl_xor(a3, off, 64);
        a4 += __shfl_xor(a4, off, 64);
        a5 += __shfl_xor(a5, off, 64);
        a6 += __shfl_xor(a6, off, 64);
        a7 += __shfl_xor(a7, off, 64);
    }
    float nd = norm_dst[node], ns = norm_src[node];
    float4 bv0 = *(const float4*)(&b1[fg * 8]);
    float4 bv1 = *(const float4*)(&b1[fg * 8 + 4]);
    float4 w0 = *(const float4*)(&W2[fg * 16 + 0]);
    float4 w1 = *(const float4*)(&W2[fg * 16 + 4]);
    float4 w2v = *(const float4*)(&W2[fg * 16 + 8]);
    float4 w3 = *(const float4*)(&W2[fg * 16 + 12]);
    float h0 = fmaxf(fmaf(a0, nd, bv0.x), 0.f) * ns;
    float h1 = fmaxf(fmaf(a1, nd, bv0.y), 0.f) * ns;
    float h2f = fmaxf(fmaf(a2, nd, bv0.z), 0.f) * ns;
    float h3 = fmaxf(fmaf(a3, nd, bv0.w), 0.f) * ns;
    float h4 = fmaxf(fmaf(a4, nd, bv1.x), 0.f) * ns;
    float h5 = fmaxf(fmaf(a5, nd, bv1.y), 0.f) * ns;
    float h6 = fmaxf(fmaf(a6, nd, bv1.z), 0.f) * ns;
    float h7 = fmaxf(fmaf(a7, nd, bv1.w), 0.f) * ns;
    float p0 = h0 * w0.x + h1 * w0.z + h2f * w1.x + h3 * w1.z +
               h4 * w2v.x + h5 * w2v.z + h6 * w3.x + h7 * w3.z;
    float p1 = h0 * w0.y + h1 * w0.w + h2f * w1.y + h3 * w1.w +
               h4 * w2v.y + h5 * w2v.w + h6 * w3.y + h7 * w3.w;
#pragma unroll
    for (int off = 1; off <= 4; off <<= 1) {
        p0 += __shfl_xor(p0, off, 64);
        p1 += __shfl_xor(p1, off, 64);
    }
    if (lane == 0) *(float2*)(&h2[node * 2]) = make_float2(p0, p1);
}

// K4: fused layer2 per dst node (one thread): agg h2 -> logits -> log_softmax
__global__ void fused2_kernel(const int* __restrict__ row_beg, const int* __restrict__ degv,
                              const int* __restrict__ csr, const float* __restrict__ h2,
                              const float* __restrict__ norm_dst, const float* __restrict__ b2,
                              float* __restrict__ out) {
    int n = blockIdx.x * blockDim.x + threadIdx.x;
    if (n >= N_NODES) return;
    int beg = row_beg[n], end = beg + degv[n];
    float s0 = 0.f, s1 = 0.f;
    for (int j = beg; j < end; ++j) {
        float2 v = *(const float2*)(&h2[csr[j] * 2]);
        s0 += v.x;
        s1 += v.y;
    }
    float nd = norm_dst[n];
    float l0 = fmaf(s0, nd, b2[0]);
    float l1 = fmaf(s1, nd, b2[1]);
    float m = fmaxf(l0, l1);
    float lse = m + logf(expf(l0 - m) + expf(l1 - m));
    *(float2*)(&out[n * 2]) = make_float2(l0 - lse, l1 - lse);
}

extern "C" void kernel_launch(void* const* d_in, const int* in_sizes, int n_in,
                              void* d_out, int out_size, void* d_ws, size_t ws_size,
                              hipStream_t stream) {
    const float* x  = (const float*)d_in[0];
    const int* src  = (const int*)d_in[1];
    const int* dst  = (const int*)d_in[2];
    const float* W1 = (const float*)d_in[3];
    const float* b1 = (const float*)d_in[4];
    const float* W2 = (const float*)d_in[5];
    const float* b2 = (const float*)d_in[6];
    float* out = (float*)d_out;
    float* ws  = (float*)d_ws;
    int*   wsi = (int*)d_ws;

    int*   cur_d    = wsi + OFF_CURD;
    int*   cur_s    = wsi + OFF_CURS;
    int*   row_beg  = wsi + OFF_RB;
    int*   degv     = wsi + OFF_DEG;
    float* norm_dst = ws + OFF_NDST;
    float* norm_src = ws + OFF_NSRC;
    unsigned short* w1t = (unsigned short*)(wsi + OFF_W1T);
    int*   dpk      = wsi + OFF_DPK;
    unsigned char* sv6 = (unsigned char*)(wsi + OFF_SV6);
    int*   csr      = wsi + OFF_CSR;
    unsigned short* hb = (unsigned short*)(wsi + OFF_HB);
    float* h2       = ws + OFF_H2;

    init_kernel<<<(INIT_N + 255) / 256, 256, 0, stream>>>(W1, cur_d, w1t);
    bscatter_kernel<<<NB_EDGE, 256, 0, stream>>>(src, dst, cur_d, cur_s, dpk, sv6);
    mid_kernel<<<NDB * 3, 256, 0, stream>>>(cur_d, cur_s, dpk, sv6, x, w1t,
                                            row_beg, degv, norm_dst, norm_src, csr, hb);
    {
        long long threads = (long long)N_NODES * 64;
        fused1_kernel<<<(int)((threads + 255) / 256), 256, 0, stream>>>(
            row_beg, degv, csr, hb, norm_dst, norm_src, b1, W2, h2);
    }
    fused2_kernel<<<(N_NODES + 255) / 256, 256, 0, stream>>>(row_beg, degv, csr, h2, norm_dst, b2, out);
}

// Round 12
// 177.944 us; speedup vs baseline: 1.0741x; 1.0359x over previous
//
#include <hip/hip_runtime.h>
#include <math.h>

#define N_NODES 50000
#define N_EDGES 800000
#define NFEAT 256
#define NHID 64
#define NCLASS 2

// buckets: node>>6 -> 782 buckets of 64 nodes
#define DB 64
#define NDB 782
#define BCAP 1536        // mean 1024, sigma 32 -> +16 sigma headroom
#define EPB 2048         // edges per scatter block (8/thread) -> 391 blocks
#define NB_EDGE ((N_EDGES + EPB - 1) / EPB)

// ---------------- workspace layout (4-byte units) ----------------
#define OFF_CURD 0        // int[800]   dst-bucket cursors (zeroed by init)
#define OFF_CURS 800      // int[800]   src-bucket cursors (zeroed by init)
#define OFF_RBD  1600     // int2[50000] (row_beg, deg) packed
#define OFF_NDST 101600   // f32[50000]
#define OFF_NSRC 151600   // f32[50000]
#define OFF_W1T  201600   // bf16[64*256] transposed W1 = 8192 words
#define OFF_DPK  209792   // int[782*1536=1201152] packed (src<<6|dst&63)
#define OFF_SV6  1410944  // uchar[1201152] (src&63) by src>>6 = 300288 words
#define OFF_CSR  1711232  // int[1201152] csr src ids
#define OFF_HB   2912384  // bf16[50000*64] = 1600000 dwords (UN-normed x@W1)
#define OFF_H2   4512384  // f32[100000]

typedef __attribute__((ext_vector_type(8))) short bf16x8;
typedef __attribute__((ext_vector_type(8))) short short8;
typedef __attribute__((ext_vector_type(4))) float f32x4;

static __device__ __forceinline__ unsigned short f2bf(float f) {
    union { float f; unsigned int u; } v; v.f = f;
    return (unsigned short)((v.u + 0x8000u) >> 16);
}
static __device__ __forceinline__ unsigned int pk2bf(float f0, float f1) {
    union { float f; unsigned int u; } a, b; a.f = f0; b.f = f1;
    return __builtin_amdgcn_perm(b.u + 0x8000u, a.u + 0x8000u, 0x07060302u);
}
static __device__ __forceinline__ float bflo(unsigned int u) {
    union { unsigned int x; float f; } v; v.x = u << 16; return v.f;
}
static __device__ __forceinline__ float bfhi(unsigned int u) {
    union { unsigned int x; float f; } v; v.x = u & 0xffff0000u; return v.f;
}

// K0: zero bucket cursors + W1 -> W1T bf16 (one launch, tiny)
#define INIT_N (1600 + NFEAT * NHID)
__global__ __launch_bounds__(256) void init_kernel(const float* __restrict__ W1,
                                                   int* __restrict__ cursors,
                                                   unsigned short* __restrict__ w1t) {
    int g = blockIdx.x * 256 + threadIdx.x;
    if (g < 1600) {
        cursors[g] = 0;
    } else if (g < INIT_N) {
        int idx = g - 1600;
        int k = idx >> 6, n = idx & 63;
        w1t[n * NFEAT + k] = f2bf(W1[idx]);
    }
}

// K1: partition edges into fixed-capacity dst-buckets (packed src<<6|dstlow)
// and src-buckets (src&63 bytes). LDS hist -> one global atomic per bucket.
__global__ __launch_bounds__(256) void bscatter_kernel(const int* __restrict__ src,
                                                       const int* __restrict__ dst,
                                                       int* __restrict__ cur_d,
                                                       int* __restrict__ cur_s,
                                                       int* __restrict__ dpk,
                                                       unsigned char* __restrict__ sv6) {
    __shared__ int hd[NDB], bd[NDB], cd[NDB], hs[NDB], bs[NDB], cs[NDB];
    int t = threadIdx.x;
    for (int i = t; i < NDB; i += 256) { hd[i] = 0; cd[i] = 0; hs[i] = 0; cs[i] = 0; }
    __syncthreads();
    int base = blockIdx.x * EPB;
    int ls[8], ld[8];
#pragma unroll
    for (int i = 0; i < 8; ++i) {
        int e = base + t + i * 256;
        ls[i] = (e < N_EDGES) ? src[e] : -1;
        ld[i] = (e < N_EDGES) ? dst[e] : -1;
        if (ld[i] >= 0) {
            atomicAdd(&hd[ld[i] >> 6], 1);
            atomicAdd(&hs[ls[i] >> 6], 1);
        }
    }
    __syncthreads();
    for (int i = t; i < NDB; i += 256) {
        if (hd[i]) bd[i] = atomicAdd(&cur_d[i], hd[i]);
        if (hs[i]) bs[i] = atomicAdd(&cur_s[i], hs[i]);
    }
    __syncthreads();
#pragma unroll
    for (int i = 0; i < 8; ++i) {
        if (ld[i] >= 0) {
            int bin = ld[i] >> 6;
            int pos = bd[bin] + atomicAdd(&cd[bin], 1);
            dpk[bin * BCAP + pos] = (ls[i] << 6) | (ld[i] & 63);
            int sbin = ls[i] >> 6;
            int spos = bs[sbin] + atomicAdd(&cs[sbin], 1);
            sv6[sbin * BCAP + spos] = (unsigned char)(ls[i] & 63);
        }
    }
}

// K2: three independent roles in one launch (all depend only on K1/K0):
//  role 0: sfin  — out-degree hist -> norm_src
//  role 1: dfin  — CSR build + norm_dst/rbdeg
//  role 2: gemm  — hb = bf16(x @ W1T), MFMA, un-normed
union MidShared {
    struct { unsigned short As[64][136]; unsigned short Bs[64][136]; } g;     // 34.8 KB
    struct { int ebuf[BCAP]; int hist4[256]; int hist[64]; int seg[64]; int cur[64]; } d;
    struct { int hist4[256]; } s;
};
__global__ __launch_bounds__(256) void mid_kernel(const int* __restrict__ cur_d,
                                                  const int* __restrict__ cur_s,
                                                  const int* __restrict__ dpk,
                                                  const unsigned char* __restrict__ sv6,
                                                  const float* __restrict__ x,
                                                  const unsigned short* __restrict__ w1t,
                                                  int2* __restrict__ rbdeg,
                                                  float* __restrict__ norm_dst,
                                                  float* __restrict__ norm_src,
                                                  int* __restrict__ csr,
                                                  unsigned short* __restrict__ hb) {
    __shared__ MidShared su;
    int t = threadIdx.x;
    int role = blockIdx.x % 3;
    int b = blockIdx.x / 3;

    if (role == 0) {
        // ---- sfin ----
        su.s.hist4[t] = 0;
        __syncthreads();
        int cnt = cur_s[b];
        int base = b * BCAP;
        int sub = (t & 3) * 64;
        for (int j = t; j < cnt; j += 256) atomicAdd(&su.s.hist4[sub + sv6[base + j]], 1);
        __syncthreads();
        if (t < 64) {
            int gid = b * 64 + t;
            if (gid < N_NODES) {
                int v = su.s.hist4[t] + su.s.hist4[64 + t] + su.s.hist4[128 + t] + su.s.hist4[192 + t];
                norm_src[gid] = rsqrtf(fmaxf((float)v, 1.0f));
            }
        }
    } else if (role == 1) {
        // ---- dfin ----
        int cnt = cur_d[b];
        int base = b * BCAP;
        if (t < 64) { su.d.hist[t] = 0; su.d.cur[t] = 0; }
        su.d.hist4[t] = 0;
        for (int j = t; j < cnt; j += 256) su.d.ebuf[j] = dpk[base + j];
        __syncthreads();
        int sub = (t & 3) * 64;
        for (int j = t; j < cnt; j += 256) atomicAdd(&su.d.hist4[sub + (su.d.ebuf[j] & 63)], 1);
        __syncthreads();
        if (t < 64) {
            int v = su.d.hist4[t] + su.d.hist4[64 + t] + su.d.hist4[128 + t] + su.d.hist4[192 + t];
            su.d.hist[t] = v;
            su.d.seg[t] = v;
        }
        __syncthreads();
#pragma unroll
        for (int off = 1; off < 64; off <<= 1) {
            int xv = 0;
            if (t < 64 && t >= off) xv = su.d.seg[t - off];
            __syncthreads();
            if (t < 64) su.d.seg[t] += xv;
            __syncthreads();
        }
        if (t < 64) {
            int v = su.d.hist[t];
            int excl = su.d.seg[t] - v;
            int gid = b * 64 + t;
            if (gid < N_NODES) {
                rbdeg[gid] = make_int2(base + excl, v);
                norm_dst[gid] = rsqrtf(fmaxf((float)v, 1.0f));
            }
            su.d.seg[t] = excl;
        }
        __syncthreads();
        for (int j = t; j < cnt; j += 256) {
            int p = su.d.ebuf[j];
            int dlow = p & 63;
            int pos = base + su.d.seg[dlow] + atomicAdd(&su.d.cur[dlow], 1);
            csr[pos] = ((unsigned)p) >> 6;
        }
    } else {
        // ---- gemm: 64-row tile, A/B staged per K-half, MFMA, un-normed hb ----
        const int row0 = b * 64;
        const int w = t >> 6;
        const int l = t & 63;
        const int m = l & 15;
        const int kq = (l >> 4) * 8;
        const int q = l >> 4;
        f32x4 acc[4] = {{0.f, 0.f, 0.f, 0.f}, {0.f, 0.f, 0.f, 0.f},
                        {0.f, 0.f, 0.f, 0.f}, {0.f, 0.f, 0.f, 0.f}};
#pragma unroll
        for (int half = 0; half < 2; ++half) {
            __syncthreads();
#pragma unroll
            for (int i = 0; i < 8; ++i) {
                int f = i * 256 + t;      // float4 id, 2048 = 64 rows x 32
                int r = f >> 5;
                int c4 = (f & 31) * 4;
                int grow = row0 + r;
                float4 av = make_float4(0.f, 0.f, 0.f, 0.f);
                if (grow < N_NODES)
                    av = *(const float4*)(&x[(size_t)grow * NFEAT + half * 128 + c4]);
                uint2 o;
                o.x = pk2bf(av.x, av.y);
                o.y = pk2bf(av.z, av.w);
                *(uint2*)(&su.g.As[r][c4]) = o;
            }
#pragma unroll
            for (int i = 0; i < 4; ++i) {
                int c = i * 256 + t;      // short8 id, 1024 = 64 rows x 16
                int n = c >> 4;
                int k8 = (c & 15) * 8;
                *(short8*)(&su.g.Bs[n][k8]) = *(const short8*)(&w1t[n * NFEAT + half * 128 + k8]);
            }
            __syncthreads();
#pragma unroll
            for (int c8 = 0; c8 < 4; ++c8) {
                int k0 = c8 * 32 + kq;
                bf16x8 a = *(const bf16x8*)(&su.g.As[w * 16 + m][k0]);
#pragma unroll
                for (int ct = 0; ct < 4; ++ct) {
                    bf16x8 bb = *(const bf16x8*)(&su.g.Bs[ct * 16 + m][k0]);
                    acc[ct] = __builtin_amdgcn_mfma_f32_16x16x32_bf16(a, bb, acc[ct], 0, 0, 0);
                }
            }
        }
#pragma unroll
        for (int reg = 0; reg < 4; ++reg) {
            int r = row0 + w * 16 + q * 4 + reg;
            if (r < N_NODES) {
#pragma unroll
                for (int ct = 0; ct < 4; ++ct)
                    hb[(size_t)r * NHID + ct * 16 + m] = f2bf(acc[ct][reg]);
            }
        }
    }
}

// K3: fused layer1, node-major, register accumulation, 32 edges in flight
// per wave (4 predicated dwordx4 x 8 edge-slots). lane = e8*8 + fg.
// hb is UN-normed -> apply norm_src[s] per edge via fmaf.
__global__ __launch_bounds__(256) void fused1_kernel(const int2* __restrict__ rbdeg,
                                                     const int* __restrict__ csr,
                                                     const unsigned short* __restrict__ hb,
                                                     const float* __restrict__ norm_dst,
                                                     const float* __restrict__ norm_src,
                                                     const float* __restrict__ b1,
                                                     const float* __restrict__ W2,
                                                     float* __restrict__ h2) {
    int gtid = blockIdx.x * blockDim.x + threadIdx.x;
    int node = gtid >> 6;
    int lane = gtid & 63;
    if (node >= N_NODES) return;
    int e8 = lane >> 3, fg = lane & 7;
    int2 rd = rbdeg[node];
    int beg = rd.x;
    int end = beg + rd.y;
    float a0 = 0.f, a1 = 0.f, a2 = 0.f, a3 = 0.f, a4 = 0.f, a5 = 0.f, a6 = 0.f, a7 = 0.f;
    for (int j = beg; j < end; j += 32) {
        int j0 = j + e8, j1 = j0 + 8, j2 = j0 + 16, j3 = j0 + 24;
        uint4 u0 = make_uint4(0u, 0u, 0u, 0u), u1 = make_uint4(0u, 0u, 0u, 0u);
        uint4 u2 = make_uint4(0u, 0u, 0u, 0u), u3 = make_uint4(0u, 0u, 0u, 0u);
        float ns0 = 0.f, ns1 = 0.f, ns2 = 0.f, ns3 = 0.f;
        if (j0 < end) {
            int s = csr[j0];
            ns0 = norm_src[s];
            u0 = *(const uint4*)(&hb[(size_t)s * NHID + fg * 8]);
        }
        if (j1 < end) {
            int s = csr[j1];
            ns1 = norm_src[s];
            u1 = *(const uint4*)(&hb[(size_t)s * NHID + fg * 8]);
        }
        if (j2 < end) {
            int s = csr[j2];
            ns2 = norm_src[s];
            u2 = *(const uint4*)(&hb[(size_t)s * NHID + fg * 8]);
        }
        if (j3 < end) {
            int s = csr[j3];
            ns3 = norm_src[s];
            u3 = *(const uint4*)(&hb[(size_t)s * NHID + fg * 8]);
        }
        a0 = fmaf(ns0, bflo(u0.x), fmaf(ns1, bflo(u1.x), fmaf(ns2, bflo(u2.x), fmaf(ns3, bflo(u3.x), a0))));
        a1 = fmaf(ns0, bfhi(u0.x), fmaf(ns1, bfhi(u1.x), fmaf(ns2, bfhi(u2.x), fmaf(ns3, bfhi(u3.x), a1))));
        a2 = fmaf(ns0, bflo(u0.y), fmaf(ns1, bflo(u1.y), fmaf(ns2, bflo(u2.y), fmaf(ns3, bflo(u3.y), a2))));
        a3 = fmaf(ns0, bfhi(u0.y), fmaf(ns1, bfhi(u1.y), fmaf(ns2, bfhi(u2.y), fmaf(ns3, bfhi(u3.y), a3))));
        a4 = fmaf(ns0, bflo(u0.z), fmaf(ns1, bflo(u1.z), fmaf(ns2, bflo(u2.z), fmaf(ns3, bflo(u3.z), a4))));
        a5 = fmaf(ns0, bfhi(u0.z), fmaf(ns1, bfhi(u1.z), fmaf(ns2, bfhi(u2.z), fmaf(ns3, bfhi(u3.z), a5))));
        a6 = fmaf(ns0, bflo(u0.w), fmaf(ns1, bflo(u1.w), fmaf(ns2, bflo(u2.w), fmaf(ns3, bflo(u3.w), a6))));
        a7 = fmaf(ns0, bfhi(u0.w), fmaf(ns1, bfhi(u1.w), fmaf(ns2, bfhi(u2.w), fmaf(ns3, bfhi(u3.w), a7))));
    }
#pragma unroll
    for (int off = 8; off <= 32; off <<= 1) {
        a0 += __shfl_xor(a0, off, 64);
        a1 += __shfl_xor(a1, off, 64);
        a2 += __shfl_xor(a2, off, 64);
        a3 += __shfl_xor(a3, off, 64);
        a4 += __shfl_xor(a4, off, 64);
        a5 += __shfl_xor(a5, off, 64);
        a6 += __shfl_xor(a6, off, 64);
        a7 += __shfl_xor(a7, off, 64);
    }
    float nd = norm_dst[node], ns = norm_src[node];
    float4 bv0 = *(const float4*)(&b1[fg * 8]);
    float4 bv1 = *(const float4*)(&b1[fg * 8 + 4]);
    float4 w0 = *(const float4*)(&W2[fg * 16 + 0]);
    float4 w1 = *(const float4*)(&W2[fg * 16 + 4]);
    float4 w2v = *(const float4*)(&W2[fg * 16 + 8]);
    float4 w3 = *(const float4*)(&W2[fg * 16 + 12]);
    float h0 = fmaxf(fmaf(a0, nd, bv0.x), 0.f) * ns;
    float h1 = fmaxf(fmaf(a1, nd, bv0.y), 0.f) * ns;
    float h2f = fmaxf(fmaf(a2, nd, bv0.z), 0.f) * ns;
    float h3 = fmaxf(fmaf(a3, nd, bv0.w), 0.f) * ns;
    float h4 = fmaxf(fmaf(a4, nd, bv1.x), 0.f) * ns;
    float h5 = fmaxf(fmaf(a5, nd, bv1.y), 0.f) * ns;
    float h6 = fmaxf(fmaf(a6, nd, bv1.z), 0.f) * ns;
    float h7 = fmaxf(fmaf(a7, nd, bv1.w), 0.f) * ns;
    float p0 = h0 * w0.x + h1 * w0.z + h2f * w1.x + h3 * w1.z +
               h4 * w2v.x + h5 * w2v.z + h6 * w3.x + h7 * w3.z;
    float p1 = h0 * w0.y + h1 * w0.w + h2f * w1.y + h3 * w1.w +
               h4 * w2v.y + h5 * w2v.w + h6 * w3.y + h7 * w3.w;
#pragma unroll
    for (int off = 1; off <= 4; off <<= 1) {
        p0 += __shfl_xor(p0, off, 64);
        p1 += __shfl_xor(p1, off, 64);
    }
    if (lane == 0) *(float2*)(&h2[node * 2]) = make_float2(p0, p1);
}

// K4: fused layer2: one 16-lane group per node (latency-parallel), shfl reduce,
// log_softmax epilogue. 3125 blocks.
__global__ __launch_bounds__(256) void fused2_kernel(const int2* __restrict__ rbdeg,
                                                     const int* __restrict__ csr,
                                                     const float* __restrict__ h2,
                                                     const float* __restrict__ norm_dst,
                                                     const float* __restrict__ b2,
                                                     float* __restrict__ out) {
    int gtid = blockIdx.x * blockDim.x + threadIdx.x;
    int n = gtid >> 4;
    int l16 = gtid & 15;
    if (n >= N_NODES) return;
    int2 rd = rbdeg[n];
    int beg = rd.x, end = rd.x + rd.y;
    float s0 = 0.f, s1 = 0.f;
    for (int j = beg + l16; j < end; j += 16) {
        float2 v = *(const float2*)(&h2[csr[j] * 2]);
        s0 += v.x;
        s1 += v.y;
    }
#pragma unroll
    for (int off = 1; off <= 8; off <<= 1) {
        s0 += __shfl_xor(s0, off, 16);
        s1 += __shfl_xor(s1, off, 16);
    }
    if (l16 == 0) {
        float nd = norm_dst[n];
        float l0 = fmaf(s0, nd, b2[0]);
        float l1 = fmaf(s1, nd, b2[1]);
        float m = fmaxf(l0, l1);
        float lse = m + logf(expf(l0 - m) + expf(l1 - m));
        *(float2*)(&out[n * 2]) = make_float2(l0 - lse, l1 - lse);
    }
}

extern "C" void kernel_launch(void* const* d_in, const int* in_sizes, int n_in,
                              void* d_out, int out_size, void* d_ws, size_t ws_size,
                              hipStream_t stream) {
    const float* x  = (const float*)d_in[0];
    const int* src  = (const int*)d_in[1];
    const int* dst  = (const int*)d_in[2];
    const float* W1 = (const float*)d_in[3];
    const float* b1 = (const float*)d_in[4];
    const float* W2 = (const float*)d_in[5];
    const float* b2 = (const float*)d_in[6];
    float* out = (float*)d_out;
    float* ws  = (float*)d_ws;
    int*   wsi = (int*)d_ws;

    int*   cur_d    = wsi + OFF_CURD;
    int*   cur_s    = wsi + OFF_CURS;
    int2*  rbdeg    = (int2*)(wsi + OFF_RBD);
    float* norm_dst = ws + OFF_NDST;
    float* norm_src = ws + OFF_NSRC;
    unsigned short* w1t = (unsigned short*)(wsi + OFF_W1T);
    int*   dpk      = wsi + OFF_DPK;
    unsigned char* sv6 = (unsigned char*)(wsi + OFF_SV6);
    int*   csr      = wsi + OFF_CSR;
    unsigned short* hb = (unsigned short*)(wsi + OFF_HB);
    float* h2       = ws + OFF_H2;

    init_kernel<<<(INIT_N + 255) / 256, 256, 0, stream>>>(W1, cur_d, w1t);
    bscatter_kernel<<<NB_EDGE, 256, 0, stream>>>(src, dst, cur_d, cur_s, dpk, sv6);
    mid_kernel<<<NDB * 3, 256, 0, stream>>>(cur_d, cur_s, dpk, sv6, x, w1t,
                                            rbdeg, norm_dst, norm_src, csr, hb);
    {
        long long threads = (long long)N_NODES * 64;
        fused1_kernel<<<(int)((threads + 255) / 256), 256, 0, stream>>>(
            rbdeg, csr, hb, norm_dst, norm_src, b1, W2, h2);
    }
    {
        long long threads = (long long)N_NODES * 16;
        fused2_kernel<<<(int)((threads + 255) / 256), 256, 0, stream>>>(
            rbdeg, csr, h2, norm_dst, b2, out);
    }
}

// Round 13
// 165.439 us; speedup vs baseline: 1.1552x; 1.0756x over previous
//
#include <hip/hip_runtime.h>
#include <math.h>

#define N_NODES 50000
#define N_EDGES 800000
#define NFEAT 256
#define NHID 64
#define NCLASS 2

// buckets: node>>6 -> 782 buckets of 64 nodes
#define DB 64
#define NDB 782
#define BCAP 1536        // mean 1024, sigma 32 -> +16 sigma headroom
#define EPB 2048         // edges per scatter block (8/thread) -> 391 blocks
#define NB_EDGE ((N_EDGES + EPB - 1) / EPB)

// ---------------- workspace layout (4-byte units) ----------------
#define OFF_CURD 0        // int[800]   dst-bucket cursors (zeroed by init)
#define OFF_CURS 800      // int[800]   src-bucket cursors (zeroed by init)
#define OFF_RBD  1600     // int2[50000] (row_beg, deg) packed
#define OFF_NDST 101600   // f32[50000]
#define OFF_NSRC 151600   // f32[50000]
#define OFF_W1T  201600   // bf16[64*256] transposed W1 = 8192 words
#define OFF_DPK  209792   // int[782*1536=1201152] packed (src<<6|dst&63)
#define OFF_SV6  1410944  // uchar[1201152] (src&63) by src>>6 = 300288 words
#define OFF_CSR  1711232  // int[1201152] csr src ids
#define OFF_HB   2912384  // bf16[50000*64] = 1600000 dwords (UN-normed x@W1)
#define OFF_H2   4512384  // f32[100000]

typedef __attribute__((ext_vector_type(8))) short bf16x8;
typedef __attribute__((ext_vector_type(8))) short short8;
typedef __attribute__((ext_vector_type(4))) float f32x4;

static __device__ __forceinline__ unsigned short f2bf(float f) {
    union { float f; unsigned int u; } v; v.f = f;
    return (unsigned short)((v.u + 0x8000u) >> 16);
}
static __device__ __forceinline__ unsigned int pk2bf(float f0, float f1) {
    union { float f; unsigned int u; } a, b; a.f = f0; b.f = f1;
    return __builtin_amdgcn_perm(b.u + 0x8000u, a.u + 0x8000u, 0x07060302u);
}
static __device__ __forceinline__ float bflo(unsigned int u) {
    union { unsigned int x; float f; } v; v.x = u << 16; return v.f;
}
static __device__ __forceinline__ float bfhi(unsigned int u) {
    union { unsigned int x; float f; } v; v.x = u & 0xffff0000u; return v.f;
}

// K0: zero bucket cursors + W1 -> W1T bf16 (one launch, tiny)
#define INIT_N (1600 + NFEAT * NHID)
__global__ __launch_bounds__(256) void init_kernel(const float* __restrict__ W1,
                                                   int* __restrict__ cursors,
                                                   unsigned short* __restrict__ w1t) {
    int g = blockIdx.x * 256 + threadIdx.x;
    if (g < 1600) {
        cursors[g] = 0;
    } else if (g < INIT_N) {
        int idx = g - 1600;
        int k = idx >> 6, n = idx & 63;
        w1t[n * NFEAT + k] = f2bf(W1[idx]);
    }
}

// K1: two independent roles (both depend only on K0):
//  blocks [0,391):    scatter — partition edges into dst-buckets (packed
//                     src<<6|dstlow) and src-buckets (src&63 bytes)
//  blocks [391,1173): gemm — hb = bf16(x @ W1T), MFMA, un-normed
union SgShared {
    struct { int hd[NDB], bd[NDB], cd[NDB], hs[NDB], bs[NDB], cs[NDB]; } b;   // 18.8 KB
    struct { unsigned short As[64][136]; unsigned short Bs[64][136]; } g;     // 34.8 KB
};
__global__ __launch_bounds__(256) void sg_kernel(const int* __restrict__ src,
                                                 const int* __restrict__ dst,
                                                 const float* __restrict__ x,
                                                 const unsigned short* __restrict__ w1t,
                                                 int* __restrict__ cur_d,
                                                 int* __restrict__ cur_s,
                                                 int* __restrict__ dpk,
                                                 unsigned char* __restrict__ sv6,
                                                 unsigned short* __restrict__ hb) {
    __shared__ SgShared su;
    int t = threadIdx.x;
    if (blockIdx.x < NB_EDGE) {
        // ---- scatter role ----
        for (int i = t; i < NDB; i += 256) { su.b.hd[i] = 0; su.b.cd[i] = 0; su.b.hs[i] = 0; su.b.cs[i] = 0; }
        __syncthreads();
        int base = blockIdx.x * EPB;
        int ls[8], ld[8];
#pragma unroll
        for (int i = 0; i < 8; ++i) {
            int e = base + t + i * 256;
            ls[i] = (e < N_EDGES) ? src[e] : -1;
            ld[i] = (e < N_EDGES) ? dst[e] : -1;
            if (ld[i] >= 0) {
                atomicAdd(&su.b.hd[ld[i] >> 6], 1);
                atomicAdd(&su.b.hs[ls[i] >> 6], 1);
            }
        }
        __syncthreads();
        for (int i = t; i < NDB; i += 256) {
            if (su.b.hd[i]) su.b.bd[i] = atomicAdd(&cur_d[i], su.b.hd[i]);
            if (su.b.hs[i]) su.b.bs[i] = atomicAdd(&cur_s[i], su.b.hs[i]);
        }
        __syncthreads();
#pragma unroll
        for (int i = 0; i < 8; ++i) {
            if (ld[i] >= 0) {
                int bin = ld[i] >> 6;
                int pos = su.b.bd[bin] + atomicAdd(&su.b.cd[bin], 1);
                dpk[bin * BCAP + pos] = (ls[i] << 6) | (ld[i] & 63);
                int sbin = ls[i] >> 6;
                int spos = su.b.bs[sbin] + atomicAdd(&su.b.cs[sbin], 1);
                sv6[sbin * BCAP + spos] = (unsigned char)(ls[i] & 63);
            }
        }
    } else {
        // ---- gemm role: 64-row tile, A/B staged per K-half, MFMA ----
        const int b = blockIdx.x - NB_EDGE;
        const int row0 = b * 64;
        const int w = t >> 6;
        const int l = t & 63;
        const int m = l & 15;
        const int kq = (l >> 4) * 8;
        const int q = l >> 4;
        f32x4 acc[4] = {{0.f, 0.f, 0.f, 0.f}, {0.f, 0.f, 0.f, 0.f},
                        {0.f, 0.f, 0.f, 0.f}, {0.f, 0.f, 0.f, 0.f}};
#pragma unroll
        for (int half = 0; half < 2; ++half) {
            __syncthreads();
#pragma unroll
            for (int i = 0; i < 8; ++i) {
                int f = i * 256 + t;      // float4 id, 2048 = 64 rows x 32
                int r = f >> 5;
                int c4 = (f & 31) * 4;
                int grow = row0 + r;
                float4 av = make_float4(0.f, 0.f, 0.f, 0.f);
                if (grow < N_NODES)
                    av = *(const float4*)(&x[(size_t)grow * NFEAT + half * 128 + c4]);
                uint2 o;
                o.x = pk2bf(av.x, av.y);
                o.y = pk2bf(av.z, av.w);
                *(uint2*)(&su.g.As[r][c4]) = o;
            }
#pragma unroll
            for (int i = 0; i < 4; ++i) {
                int c = i * 256 + t;      // short8 id, 1024 = 64 rows x 16
                int n = c >> 4;
                int k8 = (c & 15) * 8;
                *(short8*)(&su.g.Bs[n][k8]) = *(const short8*)(&w1t[n * NFEAT + half * 128 + k8]);
            }
            __syncthreads();
#pragma unroll
            for (int c8 = 0; c8 < 4; ++c8) {
                int k0 = c8 * 32 + kq;
                bf16x8 a = *(const bf16x8*)(&su.g.As[w * 16 + m][k0]);
#pragma unroll
                for (int ct = 0; ct < 4; ++ct) {
                    bf16x8 bb = *(const bf16x8*)(&su.g.Bs[ct * 16 + m][k0]);
                    acc[ct] = __builtin_amdgcn_mfma_f32_16x16x32_bf16(a, bb, acc[ct], 0, 0, 0);
                }
            }
        }
#pragma unroll
        for (int reg = 0; reg < 4; ++reg) {
            int r = row0 + w * 16 + q * 4 + reg;
            if (r < N_NODES) {
#pragma unroll
                for (int ct = 0; ct < 4; ++ct)
                    hb[(size_t)r * NHID + ct * 16 + m] = f2bf(acc[ct][reg]);
            }
        }
    }
}

// K2: two roles (both depend on K1's scatter):
//  role 0: sfin — out-degree hist -> norm_src
//  role 1: dfin — CSR build + norm_dst/rbdeg
union FinShared {
    struct { int ebuf[BCAP]; int hist4[256]; int hist[64]; int seg[64]; int cur[64]; } d;  // 7.5 KB
    struct { int hist4[256]; } s;
};
__global__ __launch_bounds__(256) void fin_kernel(const int* __restrict__ cur_d,
                                                  const int* __restrict__ cur_s,
                                                  const int* __restrict__ dpk,
                                                  const unsigned char* __restrict__ sv6,
                                                  int2* __restrict__ rbdeg,
                                                  float* __restrict__ norm_dst,
                                                  float* __restrict__ norm_src,
                                                  int* __restrict__ csr) {
    __shared__ FinShared su;
    int t = threadIdx.x;
    int role = blockIdx.x & 1;
    int b = blockIdx.x >> 1;

    if (role == 0) {
        // ---- sfin ----
        su.s.hist4[t] = 0;
        __syncthreads();
        int cnt = cur_s[b];
        int base = b * BCAP;
        int sub = (t & 3) * 64;
        for (int j = t; j < cnt; j += 256) atomicAdd(&su.s.hist4[sub + sv6[base + j]], 1);
        __syncthreads();
        if (t < 64) {
            int gid = b * 64 + t;
            if (gid < N_NODES) {
                int v = su.s.hist4[t] + su.s.hist4[64 + t] + su.s.hist4[128 + t] + su.s.hist4[192 + t];
                norm_src[gid] = rsqrtf(fmaxf((float)v, 1.0f));
            }
        }
    } else {
        // ---- dfin ----
        int cnt = cur_d[b];
        int base = b * BCAP;
        if (t < 64) { su.d.hist[t] = 0; su.d.cur[t] = 0; }
        su.d.hist4[t] = 0;
        for (int j = t; j < cnt; j += 256) su.d.ebuf[j] = dpk[base + j];
        __syncthreads();
        int sub = (t & 3) * 64;
        for (int j = t; j < cnt; j += 256) atomicAdd(&su.d.hist4[sub + (su.d.ebuf[j] & 63)], 1);
        __syncthreads();
        if (t < 64) {
            int v = su.d.hist4[t] + su.d.hist4[64 + t] + su.d.hist4[128 + t] + su.d.hist4[192 + t];
            su.d.hist[t] = v;
            su.d.seg[t] = v;
        }
        __syncthreads();
#pragma unroll
        for (int off = 1; off < 64; off <<= 1) {
            int xv = 0;
            if (t < 64 && t >= off) xv = su.d.seg[t - off];
            __syncthreads();
            if (t < 64) su.d.seg[t] += xv;
            __syncthreads();
        }
        if (t < 64) {
            int v = su.d.hist[t];
            int excl = su.d.seg[t] - v;
            int gid = b * 64 + t;
            if (gid < N_NODES) {
                rbdeg[gid] = make_int2(base + excl, v);
                norm_dst[gid] = rsqrtf(fmaxf((float)v, 1.0f));
            }
            su.d.seg[t] = excl;
        }
        __syncthreads();
        for (int j = t; j < cnt; j += 256) {
            int p = su.d.ebuf[j];
            int dlow = p & 63;
            int pos = base + su.d.seg[dlow] + atomicAdd(&su.d.cur[dlow], 1);
            csr[pos] = ((unsigned)p) >> 6;
        }
    }
}

// K3: fused layer1, node-major, register accumulation, 32 edges in flight
// per wave (4 predicated dwordx4 x 8 edge-slots). lane = e8*8 + fg.
// hb is UN-normed -> apply norm_src[s] per edge via fmaf.
__global__ __launch_bounds__(256) void fused1_kernel(const int2* __restrict__ rbdeg,
                                                     const int* __restrict__ csr,
                                                     const unsigned short* __restrict__ hb,
                                                     const float* __restrict__ norm_dst,
                                                     const float* __restrict__ norm_src,
                                                     const float* __restrict__ b1,
                                                     const float* __restrict__ W2,
                                                     float* __restrict__ h2) {
    int gtid = blockIdx.x * blockDim.x + threadIdx.x;
    int node = gtid >> 6;
    int lane = gtid & 63;
    if (node >= N_NODES) return;
    int e8 = lane >> 3, fg = lane & 7;
    int2 rd = rbdeg[node];
    int beg = rd.x;
    int end = beg + rd.y;
    float a0 = 0.f, a1 = 0.f, a2 = 0.f, a3 = 0.f, a4 = 0.f, a5 = 0.f, a6 = 0.f, a7 = 0.f;
    for (int j = beg; j < end; j += 32) {
        int j0 = j + e8, j1 = j0 + 8, j2 = j0 + 16, j3 = j0 + 24;
        uint4 u0 = make_uint4(0u, 0u, 0u, 0u), u1 = make_uint4(0u, 0u, 0u, 0u);
        uint4 u2 = make_uint4(0u, 0u, 0u, 0u), u3 = make_uint4(0u, 0u, 0u, 0u);
        float ns0 = 0.f, ns1 = 0.f, ns2 = 0.f, ns3 = 0.f;
        if (j0 < end) {
            int s = csr[j0];
            ns0 = norm_src[s];
            u0 = *(const uint4*)(&hb[(size_t)s * NHID + fg * 8]);
        }
        if (j1 < end) {
            int s = csr[j1];
            ns1 = norm_src[s];
            u1 = *(const uint4*)(&hb[(size_t)s * NHID + fg * 8]);
        }
        if (j2 < end) {
            int s = csr[j2];
            ns2 = norm_src[s];
            u2 = *(const uint4*)(&hb[(size_t)s * NHID + fg * 8]);
        }
        if (j3 < end) {
            int s = csr[j3];
            ns3 = norm_src[s];
            u3 = *(const uint4*)(&hb[(size_t)s * NHID + fg * 8]);
        }
        a0 = fmaf(ns0, bflo(u0.x), fmaf(ns1, bflo(u1.x), fmaf(ns2, bflo(u2.x), fmaf(ns3, bflo(u3.x), a0))));
        a1 = fmaf(ns0, bfhi(u0.x), fmaf(ns1, bfhi(u1.x), fmaf(ns2, bfhi(u2.x), fmaf(ns3, bfhi(u3.x), a1))));
        a2 = fmaf(ns0, bflo(u0.y), fmaf(ns1, bflo(u1.y), fmaf(ns2, bflo(u2.y), fmaf(ns3, bflo(u3.y), a2))));
        a3 = fmaf(ns0, bfhi(u0.y), fmaf(ns1, bfhi(u1.y), fmaf(ns2, bfhi(u2.y), fmaf(ns3, bfhi(u3.y), a3))));
        a4 = fmaf(ns0, bflo(u0.z), fmaf(ns1, bflo(u1.z), fmaf(ns2, bflo(u2.z), fmaf(ns3, bflo(u3.z), a4))));
        a5 = fmaf(ns0, bfhi(u0.z), fmaf(ns1, bfhi(u1.z), fmaf(ns2, bfhi(u2.z), fmaf(ns3, bfhi(u3.z), a5))));
        a6 = fmaf(ns0, bflo(u0.w), fmaf(ns1, bflo(u1.w), fmaf(ns2, bflo(u2.w), fmaf(ns3, bflo(u3.w), a6))));
        a7 = fmaf(ns0, bfhi(u0.w), fmaf(ns1, bfhi(u1.w), fmaf(ns2, bfhi(u2.w), fmaf(ns3, bfhi(u3.w), a7))));
    }
#pragma unroll
    for (int off = 8; off <= 32; off <<= 1) {
        a0 += __shfl_xor(a0, off, 64);
        a1 += __shfl_xor(a1, off, 64);
        a2 += __shfl_xor(a2, off, 64);
        a3 += __shfl_xor(a3, off, 64);
        a4 += __shfl_xor(a4, off, 64);
        a5 += __shfl_xor(a5, off, 64);
        a6 += __shfl_xor(a6, off, 64);
        a7 += __shfl_xor(a7, off, 64);
    }
    float nd = norm_dst[node], ns = norm_src[node];
    float4 bv0 = *(const float4*)(&b1[fg * 8]);
    float4 bv1 = *(const float4*)(&b1[fg * 8 + 4]);
    float4 w0 = *(const float4*)(&W2[fg * 16 + 0]);
    float4 w1 = *(const float4*)(&W2[fg * 16 + 4]);
    float4 w2v = *(const float4*)(&W2[fg * 16 + 8]);
    float4 w3 = *(const float4*)(&W2[fg * 16 + 12]);
    float h0 = fmaxf(fmaf(a0, nd, bv0.x), 0.f) * ns;
    float h1 = fmaxf(fmaf(a1, nd, bv0.y), 0.f) * ns;
    float h2f = fmaxf(fmaf(a2, nd, bv0.z), 0.f) * ns;
    float h3 = fmaxf(fmaf(a3, nd, bv0.w), 0.f) * ns;
    float h4 = fmaxf(fmaf(a4, nd, bv1.x), 0.f) * ns;
    float h5 = fmaxf(fmaf(a5, nd, bv1.y), 0.f) * ns;
    float h6 = fmaxf(fmaf(a6, nd, bv1.z), 0.f) * ns;
    float h7 = fmaxf(fmaf(a7, nd, bv1.w), 0.f) * ns;
    float p0 = h0 * w0.x + h1 * w0.z + h2f * w1.x + h3 * w1.z +
               h4 * w2v.x + h5 * w2v.z + h6 * w3.x + h7 * w3.z;
    float p1 = h0 * w0.y + h1 * w0.w + h2f * w1.y + h3 * w1.w +
               h4 * w2v.y + h5 * w2v.w + h6 * w3.y + h7 * w3.w;
#pragma unroll
    for (int off = 1; off <= 4; off <<= 1) {
        p0 += __shfl_xor(p0, off, 64);
        p1 += __shfl_xor(p1, off, 64);
    }
    if (lane == 0) *(float2*)(&h2[node * 2]) = make_float2(p0, p1);
}

// K4: fused layer2: one 16-lane group per node, shfl reduce, log_softmax.
__global__ __launch_bounds__(256) void fused2_kernel(const int2* __restrict__ rbdeg,
                                                     const int* __restrict__ csr,
                                                     const float* __restrict__ h2,
                                                     const float* __restrict__ norm_dst,
                                                     const float* __restrict__ b2,
                                                     float* __restrict__ out) {
    int gtid = blockIdx.x * blockDim.x + threadIdx.x;
    int n = gtid >> 4;
    int l16 = gtid & 15;
    if (n >= N_NODES) return;
    int2 rd = rbdeg[n];
    int beg = rd.x, end = rd.x + rd.y;
    float s0 = 0.f, s1 = 0.f;
    for (int j = beg + l16; j < end; j += 16) {
        float2 v = *(const float2*)(&h2[csr[j] * 2]);
        s0 += v.x;
        s1 += v.y;
    }
#pragma unroll
    for (int off = 1; off <= 8; off <<= 1) {
        s0 += __shfl_xor(s0, off, 16);
        s1 += __shfl_xor(s1, off, 16);
    }
    if (l16 == 0) {
        float nd = norm_dst[n];
        float l0 = fmaf(s0, nd, b2[0]);
        float l1 = fmaf(s1, nd, b2[1]);
        float m = fmaxf(l0, l1);
        float lse = m + logf(expf(l0 - m) + expf(l1 - m));
        *(float2*)(&out[n * 2]) = make_float2(l0 - lse, l1 - lse);
    }
}

extern "C" void kernel_launch(void* const* d_in, const int* in_sizes, int n_in,
                              void* d_out, int out_size, void* d_ws, size_t ws_size,
                              hipStream_t stream) {
    const float* x  = (const float*)d_in[0];
    const int* src  = (const int*)d_in[1];
    const int* dst  = (const int*)d_in[2];
    const float* W1 = (const float*)d_in[3];
    const float* b1 = (const float*)d_in[4];
    const float* W2 = (const float*)d_in[5];
    const float* b2 = (const float*)d_in[6];
    float* out = (float*)d_out;
    float* ws  = (float*)d_ws;
    int*   wsi = (int*)d_ws;

    int*   cur_d    = wsi + OFF_CURD;
    int*   cur_s    = wsi + OFF_CURS;
    int2*  rbdeg    = (int2*)(wsi + OFF_RBD);
    float* norm_dst = ws + OFF_NDST;
    float* norm_src = ws + OFF_NSRC;
    unsigned short* w1t = (unsigned short*)(wsi + OFF_W1T);
    int*   dpk      = wsi + OFF_DPK;
    unsigned char* sv6 = (unsigned char*)(wsi + OFF_SV6);
    int*   csr      = wsi + OFF_CSR;
    unsigned short* hb = (unsigned short*)(wsi + OFF_HB);
    float* h2       = ws + OFF_H2;

    init_kernel<<<(INIT_N + 255) / 256, 256, 0, stream>>>(W1, cur_d, w1t);
    sg_kernel<<<NB_EDGE + NDB, 256, 0, stream>>>(src, dst, x, w1t, cur_d, cur_s, dpk, sv6, hb);
    fin_kernel<<<NDB * 2, 256, 0, stream>>>(cur_d, cur_s, dpk, sv6, rbdeg, norm_dst, norm_src, csr);
    {
        long long threads = (long long)N_NODES * 64;
        fused1_kernel<<<(int)((threads + 255) / 256), 256, 0, stream>>>(
            rbdeg, csr, hb, norm_dst, norm_src, b1, W2, h2);
    }
    {
        long long threads = (long long)N_NODES * 16;
        fused2_kernel<<<(int)((threads + 255) / 256), 256, 0, stream>>>(
            rbdeg, csr, h2, norm_dst, b2, out);
    }
}